// Round 1
// baseline (535.561 us; speedup 1.0000x reference)
//
#include <hip/hip_runtime.h>
#include <math.h>

#define N_DETC 128
#define N_TC   2048
#define N_FC   1025
#define NXC    128
#define NYC    256
#define NBCC   16     // B*C = 8*2

__device__ __forceinline__ float2 cmulf(float2 a, float2 b){
    return make_float2(a.x*b.x - a.y*b.y, a.x*b.y + a.y*b.x);
}

// ---------------- stats: per-(b,c) mean & inv-std ----------------
__global__ __launch_bounds__(256) void k_stats(const float* __restrict__ sino,
                                               float* __restrict__ stat){
    int bc = blockIdx.x;
    const float* p = sino + (size_t)bc * (N_DETC * N_TC);
    float s = 0.f, sq = 0.f;
    for (int i = threadIdx.x; i < N_DETC * N_TC; i += 256){
        float v = p[i];
        s += v; sq += v * v;
    }
    __shared__ float ls[256], lq[256];
    ls[threadIdx.x] = s; lq[threadIdx.x] = sq;
    __syncthreads();
    for (int off = 128; off; off >>= 1){
        if (threadIdx.x < off){
            ls[threadIdx.x] += ls[threadIdx.x + off];
            lq[threadIdx.x] += lq[threadIdx.x + off];
        }
        __syncthreads();
    }
    if (threadIdx.x == 0){
        const float inv_n = 1.f / (float)(N_DETC * N_TC);
        float mean = ls[0] * inv_n;
        float var  = lq[0] * inv_n - mean * mean;
        stat[bc]      = mean;
        stat[16 + bc] = rsqrtf(fmaxf(var, 0.f) + 1.1920929e-7f);
    }
}

// ---------------- apod sum ----------------
__global__ void k_apod(const float* __restrict__ apod, float* __restrict__ stat){
    __shared__ float ls[128];
    ls[threadIdx.x] = apod[threadIdx.x];
    __syncthreads();
    for (int off = 64; off; off >>= 1){
        if (threadIdx.x < off) ls[threadIdx.x] += ls[threadIdx.x + off];
        __syncthreads();
    }
    if (threadIdx.x == 0) stat[32] = ls[0];
}

// ---------------- tables: step = exp(i*DY*kz), p0 = exp(i*Y0*kz) per (kd,f) ----------------
__global__ __launch_bounds__(256) void k_tables(float2* __restrict__ step,
                                                float2* __restrict__ p0){
    int idx = blockIdx.x * 256 + threadIdx.x;
    if (idx >= N_DETC * N_FC) return;
    int kd = idx / N_FC;
    int f  = idx - kd * N_FC;
    float freqf = (float)((double)f / (2048.0 * 2.5e-8));
    float omega = (float)(2.0 * M_PI) * freqf;
    float oc = omega / 1540.0f;
    int sdx = (kd < 64) ? kd : kd - 128;
    float kx = (float)(2.0 * M_PI * ((double)sdx / (128.0 * 3.0e-4)));
    float kzsq = oc * oc - kx * kx;
    float kz = (kzsq > 0.f) ? sqrtf(kzsq) : 0.f;
    float s0, c0, s1, c1;
    sincosf(1.0e-3f * kz, &s0, &c0);   // Y0 * kz
    sincosf(1.5e-4f * kz, &s1, &c1);   // DY * kz
    p0[idx]   = make_float2(c0, s0);
    step[idx] = make_float2(c1, s1);
}

// ---------------- temporal FFT: 2048-pt complex FFT (imag=0), keep bins 0..1024 ----------------
__global__ __launch_bounds__(256) void k_tfft(const float* __restrict__ sino,
                                              const float* __restrict__ apod,
                                              const float* __restrict__ stat,
                                              float2* __restrict__ spec){
    int row = blockIdx.x;            // bc*128 + d
    int bc = row >> 7, d = row & 127;
    __shared__ float2 a[N_TC];       // 16 KB
    float mean = stat[bc];
    float scl  = stat[16 + bc] * apod[d];
    const float* p = sino + (size_t)row * N_TC;
    for (int t = threadIdx.x; t < N_TC; t += 256){
        float v = (p[t] - mean) * scl;
        int r = __brev((unsigned)t) >> 21;   // 11-bit reverse
        a[r] = make_float2(v, 0.f);
    }
    __syncthreads();
    for (int s = 1; s <= 11; ++s){
        int half = 1 << (s - 1);
        for (int j = threadIdx.x; j < N_TC / 2; j += 256){
            int g = j >> (s - 1);
            int k = j & (half - 1);
            int i1 = (g << s) + k;
            int i2 = i1 + half;
            float ang = -(float)M_PI * (float)k / (float)half;   // -2*pi*k/m
            float sn, cs; __sincosf(ang, &sn, &cs);
            float2 u = a[i1], v = a[i2];
            float2 t = make_float2(v.x * cs - v.y * sn, v.x * sn + v.y * cs);
            a[i1] = make_float2(u.x + t.x, u.y + t.y);
            a[i2] = make_float2(u.x - t.x, u.y - t.y);
        }
        __syncthreads();
    }
    float2* o = spec + (size_t)row * N_FC;
    for (int f = threadIdx.x; f < N_FC; f += 256) o[f] = a[f];
}

// ---------------- detector FFT (128-pt, in-place over d axis) + mask & freq weight ----------------
__global__ __launch_bounds__(256) void k_dfft(float2* __restrict__ spec){
    int bc = blockIdx.x / 257;
    int fg = blockIdx.x - bc * 257;
    int w    = threadIdx.x >> 6;     // wave id 0..3 -> one f column each
    int lane = threadIdx.x & 63;
    int ftry = fg * 4 + w;
    bool valid = (ftry <= 1024);
    int f = valid ? ftry : 1024;
    __shared__ float2 col[4][128];
    float2* base = spec + (size_t)bc * 128 * N_FC + f;
    col[w][__brev((unsigned)lane) >> 25]        = base[(size_t)lane * N_FC];
    col[w][__brev((unsigned)(lane + 64)) >> 25] = base[(size_t)(lane + 64) * N_FC];
    __syncthreads();
    for (int s = 1; s <= 7; ++s){
        int half = 1 << (s - 1);
        int g = lane >> (s - 1);
        int k = lane & (half - 1);
        int i1 = (g << s) + k;
        int i2 = i1 + half;
        float ang = -(float)M_PI * (float)k / (float)half;
        float sn, cs; __sincosf(ang, &sn, &cs);
        float2 u = col[w][i1], v = col[w][i2];
        float2 t = make_float2(v.x * cs - v.y * sn, v.x * sn + v.y * cs);
        col[w][i1] = make_float2(u.x + t.x, u.y + t.y);
        col[w][i2] = make_float2(u.x - t.x, u.y - t.y);
        __syncthreads();
    }
    if (valid){
        float freqf = (float)((double)f / (2048.0 * 2.5e-8));
        float omega = (float)(2.0 * M_PI) * freqf;
        float oc = omega / 1540.0f;
        float fw = (f == 0 || f == 1024) ? 1.f : 2.f;
        #pragma unroll
        for (int kk = 0; kk < 2; ++kk){
            int kd = lane + kk * 64;
            int sdx = (kd < 64) ? kd : kd - 128;
            float kx = (float)(2.0 * M_PI * ((double)sdx / (128.0 * 3.0e-4)));
            float m = (oc * oc - kx * kx > 0.f) ? fw : 0.f;
            float2 vv = col[w][kd];
            base[(size_t)kd * N_FC] = make_float2(vv.x * m, vv.y * m);
        }
    }
}

// ---------------- band: band[bc][y][kd] = sum_f specw * exp(i*y*kz), phase recurrence ----------------
__global__ __launch_bounds__(256) void k_band(const float2* __restrict__ spec,
                                              const float2* __restrict__ step,
                                              const float2* __restrict__ p0,
                                              float2* __restrict__ band){
    int wid  = (blockIdx.x << 2) + (threadIdx.x >> 6);   // 0..2047 : bc*128 + kd
    int lane = threadIdx.x & 63;
    int kd = wid & 127, bc = wid >> 7;
    const float2* sp = spec + (size_t)(bc * 128 + kd) * N_FC;
    const float2* st = step + (size_t)kd * N_FC;
    const float2* pp = p0   + (size_t)kd * N_FC;
    float2 sw[17], stp[17], ph[17];
    #pragma unroll
    for (int k = 0; k < 17; ++k){
        int f = lane + (k << 6);
        if (f <= 1024){ sw[k] = sp[f]; stp[k] = st[f]; ph[k] = pp[f]; }
        else          { sw[k] = make_float2(0.f, 0.f); stp[k] = make_float2(1.f, 0.f); ph[k] = make_float2(1.f, 0.f); }
    }
    float2* ob = band + (size_t)bc * NYC * 128 + kd;
    for (int y = 0; y < NYC; ++y){
        float ar = 0.f, ai = 0.f;
        #pragma unroll
        for (int k = 0; k < 17; ++k){
            ar += sw[k].x * ph[k].x - sw[k].y * ph[k].y;
            ai += sw[k].x * ph[k].y + sw[k].y * ph[k].x;
        }
        #pragma unroll
        for (int k = 0; k < 17; ++k){
            float nr = ph[k].x * stp[k].x - ph[k].y * stp[k].y;
            float ni = ph[k].x * stp[k].y + ph[k].y * stp[k].x;
            ph[k].x = nr; ph[k].y = ni;
        }
        #pragma unroll
        for (int m = 1; m < 64; m <<= 1){
            ar += __shfl_xor(ar, m, 64);
            ai += __shfl_xor(ai, m, 64);
        }
        if (lane == 0) ob[(size_t)y * 128] = make_float2(ar, ai);
    }
}

// ---------------- final: 128-pt inverse DFT over kd + magnitude + norm ----------------
__global__ __launch_bounds__(256) void k_final(const float2* __restrict__ band,
                                               const float* __restrict__ stat,
                                               float* __restrict__ out){
    int blk = blockIdx.x;            // bc*128 + ypair
    int bc = blk >> 7, yp = blk & 127;
    int r = threadIdx.x >> 7;        // 0/1 : which y of the pair
    int x = threadIdx.x & 127;
    int y = yp * 2 + r;
    __shared__ float2 row[2][128];
    row[r][x] = band[((size_t)bc * NYC + y) * 128 + x];
    __syncthreads();
    float ang = (float)(2.0 * M_PI / 128.0) * (float)x;
    float sn, cs; sincosf(ang, &sn, &cs);
    float2 wx = make_float2(cs, sn);
    float2 p  = make_float2(1.f, 0.f);
    float ar = 0.f, ai = 0.f;
    for (int kd = 0; kd < 128; ++kd){
        float2 b = row[r][kd];
        ar += b.x * p.x - b.y * p.y;
        ai += b.x * p.y + b.y * p.x;
        p = cmulf(p, wx);
    }
    float invnorm = 1.f / (fmaxf(stat[32], 1.1920929e-7f) * 2048.f);
    out[((size_t)bc * NYC + y) * 128 + x] = sqrtf(ar * ar + ai * ai) * invnorm;
}

extern "C" void kernel_launch(void* const* d_in, const int* in_sizes, int n_in,
                              void* d_out, int out_size, void* d_ws, size_t ws_size,
                              hipStream_t stream){
    const float* sino = (const float*)d_in[0];
    const float* apod = (const float*)d_in[1];
    float* out = (float*)d_out;
    float* W = (float*)d_ws;
    // workspace layout (floats): [0..63] stats, then step/p0 tables, spec, band
    float2* step = (float2*)(W + 64);
    float2* p0   = step + (size_t)N_DETC * N_FC;
    float2* spec = p0   + (size_t)N_DETC * N_FC;
    float2* band = spec + (size_t)NBCC * N_DETC * N_FC;

    k_stats <<<NBCC, 256, 0, stream>>>(sino, W);
    k_apod  <<<1, 128, 0, stream>>>(apod, W);
    k_tables<<<(N_DETC * N_FC + 255) / 256, 256, 0, stream>>>(step, p0);
    k_tfft  <<<NBCC * N_DETC, 256, 0, stream>>>(sino, apod, W, spec);
    k_dfft  <<<NBCC * 257, 256, 0, stream>>>(spec);
    k_band  <<<512, 256, 0, stream>>>(spec, step, p0, band);
    k_final <<<NBCC * NXC, 256, 0, stream>>>(band, W, out);
}

// Round 2
// 273.394 us; speedup vs baseline: 1.9589x; 1.9589x over previous
//
#include <hip/hip_runtime.h>
#include <math.h>

#define N_DETC 128
#define N_TC   2048
#define N_FC   1025
#define NXC    128
#define NYC    256
#define NBCC   16     // B*C = 8*2

__device__ __forceinline__ float2 cmulf(float2 a, float2 b){
    return make_float2(a.x*b.x - a.y*b.y, a.x*b.y + a.y*b.x);
}

// ---------------- stats stage 1: per-(bc,chunk) partial sums, float4 loads ----------------
__global__ __launch_bounds__(256) void k_stats1(const float* __restrict__ sino,
                                                float* __restrict__ psum,
                                                float* __restrict__ psq){
    int bc    = blockIdx.x >> 6;
    int chunk = blockIdx.x & 63;
    const float4* p = (const float4*)(sino + (size_t)bc * (N_DETC * N_TC)) + (size_t)chunk * 1024;
    float s = 0.f, q = 0.f;
    #pragma unroll
    for (int i = 0; i < 4; ++i){
        float4 v = p[threadIdx.x + i * 256];
        s += v.x + v.y + v.z + v.w;
        q += v.x*v.x + v.y*v.y + v.z*v.z + v.w*v.w;
    }
    #pragma unroll
    for (int m = 1; m < 64; m <<= 1){
        s += __shfl_xor(s, m, 64);
        q += __shfl_xor(q, m, 64);
    }
    __shared__ float ls[4], lq[4];
    int w = threadIdx.x >> 6, lane = threadIdx.x & 63;
    if (lane == 0){ ls[w] = s; lq[w] = q; }
    __syncthreads();
    if (threadIdx.x == 0){
        psum[blockIdx.x] = ls[0] + ls[1] + ls[2] + ls[3];
        psq[blockIdx.x]  = lq[0] + lq[1] + lq[2] + lq[3];
    }
}

// ---------------- stats stage 2: finalize mean & inv-std per bc ----------------
__global__ void k_stats2(const float* __restrict__ psum,
                         const float* __restrict__ psq,
                         float* __restrict__ stat){
    int bc = blockIdx.x, t = threadIdx.x;   // 64 threads
    float s = psum[bc * 64 + t], q = psq[bc * 64 + t];
    #pragma unroll
    for (int m = 1; m < 64; m <<= 1){
        s += __shfl_xor(s, m, 64);
        q += __shfl_xor(q, m, 64);
    }
    if (t == 0){
        const float inv_n = 1.f / (float)(N_DETC * N_TC);
        float mean = s * inv_n;
        float var  = q * inv_n - mean * mean;
        stat[bc]      = mean;
        stat[16 + bc] = rsqrtf(fmaxf(var, 0.f) + 1.1920929e-7f);
    }
}

// ---------------- apod sum ----------------
__global__ void k_apod(const float* __restrict__ apod, float* __restrict__ stat){
    __shared__ float ls[128];
    ls[threadIdx.x] = apod[threadIdx.x];
    __syncthreads();
    for (int off = 64; off; off >>= 1){
        if (threadIdx.x < off) ls[threadIdx.x] += ls[threadIdx.x + off];
        __syncthreads();
    }
    if (threadIdx.x == 0) stat[32] = ls[0];
}

// ---------------- tables: step = exp(i*DY*kz), p0 = exp(i*Y0*kz) per (kd,f) ----------------
__global__ __launch_bounds__(256) void k_tables(float2* __restrict__ step,
                                                float2* __restrict__ p0){
    int idx = blockIdx.x * 256 + threadIdx.x;
    if (idx >= N_DETC * N_FC) return;
    int kd = idx / N_FC;
    int f  = idx - kd * N_FC;
    float freqf = (float)((double)f / (2048.0 * 2.5e-8));
    float omega = (float)(2.0 * M_PI) * freqf;
    float oc = omega / 1540.0f;
    int sdx = (kd < 64) ? kd : kd - 128;
    float kx = (float)(2.0 * M_PI * ((double)sdx / (128.0 * 3.0e-4)));
    float kzsq = oc * oc - kx * kx;
    float kz = (kzsq > 0.f) ? sqrtf(kzsq) : 0.f;
    float s0, c0, s1, c1;
    sincosf(1.0e-3f * kz, &s0, &c0);   // Y0 * kz
    sincosf(1.5e-4f * kz, &s1, &c1);   // DY * kz
    p0[idx]   = make_float2(c0, s0);
    step[idx] = make_float2(c1, s1);
}

// ---------------- temporal FFT: 2048-pt complex FFT (imag=0), keep bins 0..1024 ----------------
__global__ __launch_bounds__(256) void k_tfft(const float* __restrict__ sino,
                                              const float* __restrict__ apod,
                                              const float* __restrict__ stat,
                                              float2* __restrict__ spec){
    int row = blockIdx.x;            // bc*128 + d
    int bc = row >> 7, d = row & 127;
    __shared__ float2 a[N_TC];       // 16 KB
    float mean = stat[bc];
    float scl  = stat[16 + bc] * apod[d];
    const float* p = sino + (size_t)row * N_TC;
    for (int t = threadIdx.x; t < N_TC; t += 256){
        float v = (p[t] - mean) * scl;
        int r = __brev((unsigned)t) >> 21;   // 11-bit reverse
        a[r] = make_float2(v, 0.f);
    }
    __syncthreads();
    for (int s = 1; s <= 11; ++s){
        int half = 1 << (s - 1);
        for (int j = threadIdx.x; j < N_TC / 2; j += 256){
            int g = j >> (s - 1);
            int k = j & (half - 1);
            int i1 = (g << s) + k;
            int i2 = i1 + half;
            float ang = -(float)M_PI * (float)k / (float)half;   // -2*pi*k/m
            float sn, cs; __sincosf(ang, &sn, &cs);
            float2 u = a[i1], v = a[i2];
            float2 t = make_float2(v.x * cs - v.y * sn, v.x * sn + v.y * cs);
            a[i1] = make_float2(u.x + t.x, u.y + t.y);
            a[i2] = make_float2(u.x - t.x, u.y - t.y);
        }
        __syncthreads();
    }
    float2* o = spec + (size_t)row * N_FC;
    for (int f = threadIdx.x; f < N_FC; f += 256) o[f] = a[f];
}

// ---------------- detector FFT (128-pt, in-place over d axis) + mask & freq weight ----------------
__global__ __launch_bounds__(256) void k_dfft(float2* __restrict__ spec){
    int bc = blockIdx.x / 257;
    int fg = blockIdx.x - bc * 257;
    int w    = threadIdx.x >> 6;     // wave id 0..3 -> one f column each
    int lane = threadIdx.x & 63;
    int ftry = fg * 4 + w;
    bool valid = (ftry <= 1024);
    int f = valid ? ftry : 1024;
    __shared__ float2 col[4][128];
    float2* base = spec + (size_t)bc * 128 * N_FC + f;
    col[w][__brev((unsigned)lane) >> 25]        = base[(size_t)lane * N_FC];
    col[w][__brev((unsigned)(lane + 64)) >> 25] = base[(size_t)(lane + 64) * N_FC];
    __syncthreads();
    for (int s = 1; s <= 7; ++s){
        int half = 1 << (s - 1);
        int g = lane >> (s - 1);
        int k = lane & (half - 1);
        int i1 = (g << s) + k;
        int i2 = i1 + half;
        float ang = -(float)M_PI * (float)k / (float)half;
        float sn, cs; __sincosf(ang, &sn, &cs);
        float2 u = col[w][i1], v = col[w][i2];
        float2 t = make_float2(v.x * cs - v.y * sn, v.x * sn + v.y * cs);
        col[w][i1] = make_float2(u.x + t.x, u.y + t.y);
        col[w][i2] = make_float2(u.x - t.x, u.y - t.y);
        __syncthreads();
    }
    if (valid){
        float freqf = (float)((double)f / (2048.0 * 2.5e-8));
        float omega = (float)(2.0 * M_PI) * freqf;
        float oc = omega / 1540.0f;
        float fw = (f == 0 || f == 1024) ? 1.f : 2.f;
        #pragma unroll
        for (int kk = 0; kk < 2; ++kk){
            int kd = lane + kk * 64;
            int sdx = (kd < 64) ? kd : kd - 128;
            float kx = (float)(2.0 * M_PI * ((double)sdx / (128.0 * 3.0e-4)));
            float m = (oc * oc - kx * kx > 0.f) ? fw : 0.f;
            float2 vv = col[w][kd];
            base[(size_t)kd * N_FC] = make_float2(vv.x * m, vv.y * m);
        }
    }
}

// ---------------- band: band[bc][y][kd] = sum_f specw * exp(i*y*kz), phase recurrence ----------------
__global__ __launch_bounds__(256) void k_band(const float2* __restrict__ spec,
                                              const float2* __restrict__ step,
                                              const float2* __restrict__ p0,
                                              float2* __restrict__ band){
    int wid  = (blockIdx.x << 2) + (threadIdx.x >> 6);   // 0..2047 : bc*128 + kd
    int lane = threadIdx.x & 63;
    int kd = wid & 127, bc = wid >> 7;
    const float2* sp = spec + (size_t)(bc * 128 + kd) * N_FC;
    const float2* st = step + (size_t)kd * N_FC;
    const float2* pp = p0   + (size_t)kd * N_FC;
    float2 sw[17], stp[17], ph[17];
    #pragma unroll
    for (int k = 0; k < 17; ++k){
        int f = lane + (k << 6);
        if (f <= 1024){ sw[k] = sp[f]; stp[k] = st[f]; ph[k] = pp[f]; }
        else          { sw[k] = make_float2(0.f, 0.f); stp[k] = make_float2(1.f, 0.f); ph[k] = make_float2(1.f, 0.f); }
    }
    float2* ob = band + (size_t)bc * NYC * 128 + kd;
    for (int y = 0; y < NYC; ++y){
        float ar = 0.f, ai = 0.f;
        #pragma unroll
        for (int k = 0; k < 17; ++k){
            ar += sw[k].x * ph[k].x - sw[k].y * ph[k].y;
            ai += sw[k].x * ph[k].y + sw[k].y * ph[k].x;
        }
        #pragma unroll
        for (int k = 0; k < 17; ++k){
            float nr = ph[k].x * stp[k].x - ph[k].y * stp[k].y;
            float ni = ph[k].x * stp[k].y + ph[k].y * stp[k].x;
            ph[k].x = nr; ph[k].y = ni;
        }
        #pragma unroll
        for (int m = 1; m < 64; m <<= 1){
            ar += __shfl_xor(ar, m, 64);
            ai += __shfl_xor(ai, m, 64);
        }
        if (lane == 0) ob[(size_t)y * 128] = make_float2(ar, ai);
    }
}

// ---------------- final: 128-pt inverse DFT over kd + magnitude + norm ----------------
__global__ __launch_bounds__(256) void k_final(const float2* __restrict__ band,
                                               const float* __restrict__ stat,
                                               float* __restrict__ out){
    int blk = blockIdx.x;            // bc*128 + ypair
    int bc = blk >> 7, yp = blk & 127;
    int r = threadIdx.x >> 7;        // 0/1 : which y of the pair
    int x = threadIdx.x & 127;
    int y = yp * 2 + r;
    __shared__ float2 row[2][128];
    row[r][x] = band[((size_t)bc * NYC + y) * 128 + x];
    __syncthreads();
    float ang = (float)(2.0 * M_PI / 128.0) * (float)x;
    float sn, cs; sincosf(ang, &sn, &cs);
    float2 wx = make_float2(cs, sn);
    float2 p  = make_float2(1.f, 0.f);
    float ar = 0.f, ai = 0.f;
    for (int kd = 0; kd < 128; ++kd){
        float2 b = row[r][kd];
        ar += b.x * p.x - b.y * p.y;
        ai += b.x * p.y + b.y * p.x;
        p = cmulf(p, wx);
    }
    float invnorm = 1.f / (fmaxf(stat[32], 1.1920929e-7f) * 2048.f);
    out[((size_t)bc * NYC + y) * 128 + x] = sqrtf(ar * ar + ai * ai) * invnorm;
}

extern "C" void kernel_launch(void* const* d_in, const int* in_sizes, int n_in,
                              void* d_out, int out_size, void* d_ws, size_t ws_size,
                              hipStream_t stream){
    const float* sino = (const float*)d_in[0];
    const float* apod = (const float*)d_in[1];
    float* out = (float*)d_out;
    float* W = (float*)d_ws;
    // workspace layout (floats):
    //   [0..63]       stat (mean[16], invstd[16], apodsum)
    //   [64..1087]    psum (16 bc x 64 chunks)
    //   [1088..2111]  psq
    //   [2112..]      step / p0 / spec / band
    float* psum = W + 64;
    float* psq  = W + 1088;
    float2* step = (float2*)(W + 2112);
    float2* p0   = step + (size_t)N_DETC * N_FC;
    float2* spec = p0   + (size_t)N_DETC * N_FC;
    float2* band = spec + (size_t)NBCC * N_DETC * N_FC;

    k_stats1<<<NBCC * 64, 256, 0, stream>>>(sino, psum, psq);
    k_stats2<<<NBCC, 64, 0, stream>>>(psum, psq, W);
    k_apod  <<<1, 128, 0, stream>>>(apod, W);
    k_tables<<<(N_DETC * N_FC + 255) / 256, 256, 0, stream>>>(step, p0);
    k_tfft  <<<NBCC * N_DETC, 256, 0, stream>>>(sino, apod, W, spec);
    k_dfft  <<<NBCC * 257, 256, 0, stream>>>(spec);
    k_band  <<<512, 256, 0, stream>>>(spec, step, p0, band);
    k_final <<<NBCC * NXC, 256, 0, stream>>>(band, W, out);
}

// Round 3
// 250.295 us; speedup vs baseline: 2.1397x; 1.0923x over previous
//
#include <hip/hip_runtime.h>
#include <math.h>

#define N_DETC 128
#define N_TC   2048
#define N_FC   1025
#define NXC    128
#define NYC    256
#define NBCC   16     // B*C = 8*2

__device__ __forceinline__ float2 cmulf(float2 a, float2 b){
    return make_float2(a.x*b.x - a.y*b.y, a.x*b.y + a.y*b.x);
}

// ---------------- stats stage 1: per-(bc,chunk) partial sums, float4 loads ----------------
__global__ __launch_bounds__(256) void k_stats1(const float* __restrict__ sino,
                                                float* __restrict__ psum,
                                                float* __restrict__ psq){
    int bc    = blockIdx.x >> 6;
    int chunk = blockIdx.x & 63;
    const float4* p = (const float4*)(sino + (size_t)bc * (N_DETC * N_TC)) + (size_t)chunk * 1024;
    float s = 0.f, q = 0.f;
    #pragma unroll
    for (int i = 0; i < 4; ++i){
        float4 v = p[threadIdx.x + i * 256];
        s += v.x + v.y + v.z + v.w;
        q += v.x*v.x + v.y*v.y + v.z*v.z + v.w*v.w;
    }
    #pragma unroll
    for (int m = 1; m < 64; m <<= 1){
        s += __shfl_xor(s, m, 64);
        q += __shfl_xor(q, m, 64);
    }
    __shared__ float ls[4], lq[4];
    int w = threadIdx.x >> 6, lane = threadIdx.x & 63;
    if (lane == 0){ ls[w] = s; lq[w] = q; }
    __syncthreads();
    if (threadIdx.x == 0){
        psum[blockIdx.x] = ls[0] + ls[1] + ls[2] + ls[3];
        psq[blockIdx.x]  = lq[0] + lq[1] + lq[2] + lq[3];
    }
}

// ---------------- stats stage 2: finalize mean & inv-std per bc; bc0 also sums apod ----------------
__global__ void k_stats2(const float* __restrict__ psum,
                         const float* __restrict__ psq,
                         const float* __restrict__ apod,
                         float* __restrict__ stat){
    int bc = blockIdx.x, t = threadIdx.x;   // 64 threads
    float s = psum[bc * 64 + t], q = psq[bc * 64 + t];
    float a = (bc == 0) ? (apod[t] + apod[t + 64]) : 0.f;
    #pragma unroll
    for (int m = 1; m < 64; m <<= 1){
        s += __shfl_xor(s, m, 64);
        q += __shfl_xor(q, m, 64);
        a += __shfl_xor(a, m, 64);
    }
    if (t == 0){
        const float inv_n = 1.f / (float)(N_DETC * N_TC);
        float mean = s * inv_n;
        float var  = q * inv_n - mean * mean;
        stat[bc]      = mean;
        stat[16 + bc] = rsqrtf(fmaxf(var, 0.f) + 1.1920929e-7f);
        if (bc == 0) stat[32] = a;
    }
}

// ---------------- tables: step = exp(i*DY*kz); p0c[yc] = exp(i*(Y0+64*yc*DY)*kz) ----------------
__global__ __launch_bounds__(256) void k_tables(float2* __restrict__ step,
                                                float2* __restrict__ p0c){
    int idx = blockIdx.x * 256 + threadIdx.x;
    if (idx >= N_DETC * N_FC) return;
    int kd = idx / N_FC;
    int f  = idx - kd * N_FC;
    float freqf = (float)((double)f / (2048.0 * 2.5e-8));
    float omega = (float)(2.0 * M_PI) * freqf;
    float oc = omega / 1540.0f;
    int sdx = (kd < 64) ? kd : kd - 128;
    float kx = (float)(2.0 * M_PI * ((double)sdx / (128.0 * 3.0e-4)));
    float kzsq = oc * oc - kx * kx;
    float kz = (kzsq > 0.f) ? sqrtf(kzsq) : 0.f;
    float s1, c1;
    sincosf(1.5e-4f * kz, &s1, &c1);   // DY * kz
    step[idx] = make_float2(c1, s1);
    #pragma unroll
    for (int yc = 0; yc < 4; ++yc){
        float y0 = 1.0e-3f + 9.6e-3f * (float)yc;   // Y0 + yc*64*DY
        float s0, c0;
        sincosf(y0 * kz, &s0, &c0);
        p0c[(size_t)yc * (N_DETC * N_FC) + idx] = make_float2(c0, s0);
    }
}

// ---------------- temporal FFT: 2048-pt complex FFT (imag=0), keep bins 0..1024 ----------------
__global__ __launch_bounds__(256) void k_tfft(const float* __restrict__ sino,
                                              const float* __restrict__ apod,
                                              const float* __restrict__ stat,
                                              float2* __restrict__ spec){
    int row = blockIdx.x;            // bc*128 + d
    int bc = row >> 7, d = row & 127;
    __shared__ float2 a[N_TC];       // 16 KB
    float mean = stat[bc];
    float scl  = stat[16 + bc] * apod[d];
    const float* p = sino + (size_t)row * N_TC;
    for (int t = threadIdx.x; t < N_TC; t += 256){
        float v = (p[t] - mean) * scl;
        int r = __brev((unsigned)t) >> 21;   // 11-bit reverse
        a[r] = make_float2(v, 0.f);
    }
    __syncthreads();
    for (int s = 1; s <= 11; ++s){
        int half = 1 << (s - 1);
        for (int j = threadIdx.x; j < N_TC / 2; j += 256){
            int g = j >> (s - 1);
            int k = j & (half - 1);
            int i1 = (g << s) + k;
            int i2 = i1 + half;
            float ang = -(float)M_PI * (float)k / (float)half;   // -2*pi*k/m
            float sn, cs; __sincosf(ang, &sn, &cs);
            float2 u = a[i1], v = a[i2];
            float2 t = make_float2(v.x * cs - v.y * sn, v.x * sn + v.y * cs);
            a[i1] = make_float2(u.x + t.x, u.y + t.y);
            a[i2] = make_float2(u.x - t.x, u.y - t.y);
        }
        __syncthreads();
    }
    float2* o = spec + (size_t)row * N_FC;
    for (int f = threadIdx.x; f < N_FC; f += 256) o[f] = a[f];
}

// ---------------- detector FFT (128-pt, in-place over d axis) + mask & freq weight ----------------
__global__ __launch_bounds__(256) void k_dfft(float2* __restrict__ spec){
    int bc = blockIdx.x / 257;
    int fg = blockIdx.x - bc * 257;
    int w    = threadIdx.x >> 6;     // wave id 0..3 -> one f column each
    int lane = threadIdx.x & 63;
    int ftry = fg * 4 + w;
    bool valid = (ftry <= 1024);
    int f = valid ? ftry : 1024;
    __shared__ float2 col[4][128];
    float2* base = spec + (size_t)bc * 128 * N_FC + f;
    col[w][__brev((unsigned)lane) >> 25]        = base[(size_t)lane * N_FC];
    col[w][__brev((unsigned)(lane + 64)) >> 25] = base[(size_t)(lane + 64) * N_FC];
    __syncthreads();
    for (int s = 1; s <= 7; ++s){
        int half = 1 << (s - 1);
        int g = lane >> (s - 1);
        int k = lane & (half - 1);
        int i1 = (g << s) + k;
        int i2 = i1 + half;
        float ang = -(float)M_PI * (float)k / (float)half;
        float sn, cs; __sincosf(ang, &sn, &cs);
        float2 u = col[w][i1], v = col[w][i2];
        float2 t = make_float2(v.x * cs - v.y * sn, v.x * sn + v.y * cs);
        col[w][i1] = make_float2(u.x + t.x, u.y + t.y);
        col[w][i2] = make_float2(u.x - t.x, u.y - t.y);
        __syncthreads();
    }
    if (valid){
        float freqf = (float)((double)f / (2048.0 * 2.5e-8));
        float omega = (float)(2.0 * M_PI) * freqf;
        float oc = omega / 1540.0f;
        float fw = (f == 0 || f == 1024) ? 1.f : 2.f;
        #pragma unroll
        for (int kk = 0; kk < 2; ++kk){
            int kd = lane + kk * 64;
            int sdx = (kd < 64) ? kd : kd - 128;
            float kx = (float)(2.0 * M_PI * ((double)sdx / (128.0 * 3.0e-4)));
            float m = (oc * oc - kx * kx > 0.f) ? fw : 0.f;
            float2 vv = col[w][kd];
            base[(size_t)kd * N_FC] = make_float2(vv.x * m, vv.y * m);
        }
    }
}

// ---------------- band: band[bc][y][kd] = sum_f specw * exp(i*y*kz) ----------------
// wave = (bc, kd, yc); each wave does 64 y values starting at yc*64.
__global__ __launch_bounds__(256) void k_band(const float2* __restrict__ spec,
                                              const float2* __restrict__ step,
                                              const float2* __restrict__ p0c,
                                              float2* __restrict__ band){
    int w    = (blockIdx.x << 2) + (threadIdx.x >> 6);   // 0..8191
    int lane = threadIdx.x & 63;
    int yc = w & 3;
    int kd = (w >> 2) & 127;
    int bc = w >> 9;
    const float2* sp = spec + (size_t)(bc * 128 + kd) * N_FC;
    const float2* st = step + (size_t)kd * N_FC;
    const float2* pp = p0c  + ((size_t)yc * N_DETC + kd) * N_FC;
    float2 sw[17], stp[17], ph[17];
    #pragma unroll
    for (int k = 0; k < 17; ++k){
        int f = lane + (k << 6);
        if (f <= 1024){ sw[k] = sp[f]; stp[k] = st[f]; ph[k] = pp[f]; }
        else          { sw[k] = make_float2(0.f, 0.f); stp[k] = make_float2(1.f, 0.f); ph[k] = make_float2(1.f, 0.f); }
    }
    float2* ob = band + ((size_t)bc * NYC + yc * 64) * 128 + kd;
    for (int yy = 0; yy < 64; yy += 2){
        float ar0 = 0.f, ai0 = 0.f, ar1 = 0.f, ai1 = 0.f;
        #pragma unroll
        for (int k = 0; k < 17; ++k){
            ar0 += sw[k].x * ph[k].x - sw[k].y * ph[k].y;
            ai0 += sw[k].x * ph[k].y + sw[k].y * ph[k].x;
        }
        #pragma unroll
        for (int k = 0; k < 17; ++k){
            float nr = ph[k].x * stp[k].x - ph[k].y * stp[k].y;
            float ni = ph[k].x * stp[k].y + ph[k].y * stp[k].x;
            ph[k].x = nr; ph[k].y = ni;
        }
        #pragma unroll
        for (int k = 0; k < 17; ++k){
            ar1 += sw[k].x * ph[k].x - sw[k].y * ph[k].y;
            ai1 += sw[k].x * ph[k].y + sw[k].y * ph[k].x;
        }
        #pragma unroll
        for (int k = 0; k < 17; ++k){
            float nr = ph[k].x * stp[k].x - ph[k].y * stp[k].y;
            float ni = ph[k].x * stp[k].y + ph[k].y * stp[k].x;
            ph[k].x = nr; ph[k].y = ni;
        }
        #pragma unroll
        for (int m = 1; m < 64; m <<= 1){
            ar0 += __shfl_xor(ar0, m, 64);
            ai0 += __shfl_xor(ai0, m, 64);
            ar1 += __shfl_xor(ar1, m, 64);
            ai1 += __shfl_xor(ai1, m, 64);
        }
        if (lane == 0){
            ob[(size_t)yy * 128]       = make_float2(ar0, ai0);
            ob[(size_t)(yy + 1) * 128] = make_float2(ar1, ai1);
        }
    }
}

// ---------------- final: 128-pt inverse DFT over kd + magnitude + norm ----------------
__global__ __launch_bounds__(256) void k_final(const float2* __restrict__ band,
                                               const float* __restrict__ stat,
                                               float* __restrict__ out){
    int blk = blockIdx.x;            // bc*128 + ypair
    int bc = blk >> 7, yp = blk & 127;
    int r = threadIdx.x >> 7;        // 0/1 : which y of the pair
    int x = threadIdx.x & 127;
    int y = yp * 2 + r;
    __shared__ float2 row[2][128];
    row[r][x] = band[((size_t)bc * NYC + y) * 128 + x];
    __syncthreads();
    float ang = (float)(2.0 * M_PI / 128.0) * (float)x;
    float sn, cs; sincosf(ang, &sn, &cs);
    float2 wx = make_float2(cs, sn);
    float2 p  = make_float2(1.f, 0.f);
    float ar = 0.f, ai = 0.f;
    for (int kd = 0; kd < 128; ++kd){
        float2 b = row[r][kd];
        ar += b.x * p.x - b.y * p.y;
        ai += b.x * p.y + b.y * p.x;
        p = cmulf(p, wx);
    }
    float invnorm = 1.f / (fmaxf(stat[32], 1.1920929e-7f) * 2048.f);
    out[((size_t)bc * NYC + y) * 128 + x] = sqrtf(ar * ar + ai * ai) * invnorm;
}

extern "C" void kernel_launch(void* const* d_in, const int* in_sizes, int n_in,
                              void* d_out, int out_size, void* d_ws, size_t ws_size,
                              hipStream_t stream){
    const float* sino = (const float*)d_in[0];
    const float* apod = (const float*)d_in[1];
    float* out = (float*)d_out;
    float* W = (float*)d_ws;
    // workspace layout (floats):
    //   [0..63]       stat (mean[16], invstd[16], apodsum)
    //   [64..1087]    psum (16 bc x 64 chunks)
    //   [1088..2111]  psq
    //   [2112..]      step / p0c(4x) / spec / band
    float* psum = W + 64;
    float* psq  = W + 1088;
    float2* step = (float2*)(W + 2112);
    float2* p0c  = step + (size_t)N_DETC * N_FC;
    float2* spec = p0c  + (size_t)4 * N_DETC * N_FC;
    float2* band = spec + (size_t)NBCC * N_DETC * N_FC;

    k_stats1<<<NBCC * 64, 256, 0, stream>>>(sino, psum, psq);
    k_stats2<<<NBCC, 64, 0, stream>>>(psum, psq, apod, W);
    k_tables<<<(N_DETC * N_FC + 255) / 256, 256, 0, stream>>>(step, p0c);
    k_tfft  <<<NBCC * N_DETC, 256, 0, stream>>>(sino, apod, W, spec);
    k_dfft  <<<NBCC * 257, 256, 0, stream>>>(spec);
    k_band  <<<2048, 256, 0, stream>>>(spec, step, p0c, band);
    k_final <<<NBCC * NXC, 256, 0, stream>>>(band, W, out);
}

// Round 4
// 231.582 us; speedup vs baseline: 2.3126x; 1.0808x over previous
//
#include <hip/hip_runtime.h>
#include <math.h>

#define N_DETC 128
#define N_TC   2048
#define N_FC   1025
#define NXC    128
#define NYC    256
#define NBCC   16     // B*C = 8*2

__device__ __forceinline__ float2 cmulf(float2 a, float2 b){
    return make_float2(a.x*b.x - a.y*b.y, a.x*b.y + a.y*b.x);
}

#if __has_builtin(__builtin_amdgcn_sinf) && __has_builtin(__builtin_amdgcn_cosf)
__device__ __forceinline__ float sin_rev(float tf){ return __builtin_amdgcn_sinf(tf); }   // sin(2*pi*tf)
__device__ __forceinline__ float cos_rev(float tf){ return __builtin_amdgcn_cosf(tf); }
#else
__device__ __forceinline__ float sin_rev(float tf){ return __sinf(6.28318530718f * tf); }
__device__ __forceinline__ float cos_rev(float tf){ return __cosf(6.28318530718f * tf); }
#endif

// ---------------- stats stage 1: per-(bc,chunk) partial sums, float4 loads ----------------
__global__ __launch_bounds__(256) void k_stats1(const float* __restrict__ sino,
                                                float* __restrict__ psum,
                                                float* __restrict__ psq){
    int bc    = blockIdx.x >> 6;
    int chunk = blockIdx.x & 63;
    const float4* p = (const float4*)(sino + (size_t)bc * (N_DETC * N_TC)) + (size_t)chunk * 1024;
    float s = 0.f, q = 0.f;
    #pragma unroll
    for (int i = 0; i < 4; ++i){
        float4 v = p[threadIdx.x + i * 256];
        s += v.x + v.y + v.z + v.w;
        q += v.x*v.x + v.y*v.y + v.z*v.z + v.w*v.w;
    }
    #pragma unroll
    for (int m = 1; m < 64; m <<= 1){
        s += __shfl_xor(s, m, 64);
        q += __shfl_xor(q, m, 64);
    }
    __shared__ float ls[4], lq[4];
    int w = threadIdx.x >> 6, lane = threadIdx.x & 63;
    if (lane == 0){ ls[w] = s; lq[w] = q; }
    __syncthreads();
    if (threadIdx.x == 0){
        psum[blockIdx.x] = ls[0] + ls[1] + ls[2] + ls[3];
        psq[blockIdx.x]  = lq[0] + lq[1] + lq[2] + lq[3];
    }
}

// ---------------- stats stage 2: finalize mean & inv-std per bc; bc0 also sums apod ----------------
__global__ void k_stats2(const float* __restrict__ psum,
                         const float* __restrict__ psq,
                         const float* __restrict__ apod,
                         float* __restrict__ stat){
    int bc = blockIdx.x, t = threadIdx.x;   // 64 threads
    float s = psum[bc * 64 + t], q = psq[bc * 64 + t];
    float a = (bc == 0) ? (apod[t] + apod[t + 64]) : 0.f;
    #pragma unroll
    for (int m = 1; m < 64; m <<= 1){
        s += __shfl_xor(s, m, 64);
        q += __shfl_xor(q, m, 64);
        a += __shfl_xor(a, m, 64);
    }
    if (t == 0){
        const float inv_n = 1.f / (float)(N_DETC * N_TC);
        float mean = s * inv_n;
        float var  = q * inv_n - mean * mean;
        stat[bc]      = mean;
        stat[16 + bc] = rsqrtf(fmaxf(var, 0.f) + 1.1920929e-7f);
        if (bc == 0) stat[32] = a;
    }
}

// ---------------- temporal FFT: 2048-pt complex FFT (imag=0), keep bins 0..1024 ----------------
__global__ __launch_bounds__(256) void k_tfft(const float* __restrict__ sino,
                                              const float* __restrict__ apod,
                                              const float* __restrict__ stat,
                                              float2* __restrict__ spec){
    int row = blockIdx.x;            // bc*128 + d
    int bc = row >> 7, d = row & 127;
    __shared__ float2 a[N_TC];       // 16 KB
    float mean = stat[bc];
    float scl  = stat[16 + bc] * apod[d];
    const float* p = sino + (size_t)row * N_TC;
    for (int t = threadIdx.x; t < N_TC; t += 256){
        float v = (p[t] - mean) * scl;
        int r = __brev((unsigned)t) >> 21;   // 11-bit reverse
        a[r] = make_float2(v, 0.f);
    }
    __syncthreads();
    for (int s = 1; s <= 11; ++s){
        int half = 1 << (s - 1);
        for (int j = threadIdx.x; j < N_TC / 2; j += 256){
            int g = j >> (s - 1);
            int k = j & (half - 1);
            int i1 = (g << s) + k;
            int i2 = i1 + half;
            float ang = -(float)M_PI * (float)k / (float)half;   // -2*pi*k/m
            float sn, cs; __sincosf(ang, &sn, &cs);
            float2 u = a[i1], v = a[i2];
            float2 t = make_float2(v.x * cs - v.y * sn, v.x * sn + v.y * cs);
            a[i1] = make_float2(u.x + t.x, u.y + t.y);
            a[i2] = make_float2(u.x - t.x, u.y - t.y);
        }
        __syncthreads();
    }
    float2* o = spec + (size_t)row * N_FC;
    for (int f = threadIdx.x; f < N_FC; f += 256) o[f] = a[f];
}

// ---------------- detector FFT (128-pt, in-place over d axis) + mask & freq weight ----------------
__global__ __launch_bounds__(256) void k_dfft(float2* __restrict__ spec){
    int bc = blockIdx.x / 257;
    int fg = blockIdx.x - bc * 257;
    int w    = threadIdx.x >> 6;     // wave id 0..3 -> one f column each
    int lane = threadIdx.x & 63;
    int ftry = fg * 4 + w;
    bool valid = (ftry <= 1024);
    int f = valid ? ftry : 1024;
    __shared__ float2 col[4][128];
    float2* base = spec + (size_t)bc * 128 * N_FC + f;
    col[w][__brev((unsigned)lane) >> 25]        = base[(size_t)lane * N_FC];
    col[w][__brev((unsigned)(lane + 64)) >> 25] = base[(size_t)(lane + 64) * N_FC];
    __syncthreads();
    for (int s = 1; s <= 7; ++s){
        int half = 1 << (s - 1);
        int g = lane >> (s - 1);
        int k = lane & (half - 1);
        int i1 = (g << s) + k;
        int i2 = i1 + half;
        float ang = -(float)M_PI * (float)k / (float)half;
        float sn, cs; __sincosf(ang, &sn, &cs);
        float2 u = col[w][i1], v = col[w][i2];
        float2 t = make_float2(v.x * cs - v.y * sn, v.x * sn + v.y * cs);
        col[w][i1] = make_float2(u.x + t.x, u.y + t.y);
        col[w][i2] = make_float2(u.x - t.x, u.y - t.y);
        __syncthreads();
    }
    if (valid){
        float freqf = (float)((double)f / (2048.0 * 2.5e-8));
        float omega = (float)(2.0 * M_PI) * freqf;
        float oc = omega / 1540.0f;
        float fw = (f == 0 || f == 1024) ? 1.f : 2.f;
        #pragma unroll
        for (int kk = 0; kk < 2; ++kk){
            int kd = lane + kk * 64;
            int sdx = (kd < 64) ? kd : kd - 128;
            float kx = (float)(2.0 * M_PI * ((double)sdx / (128.0 * 3.0e-4)));
            float m = (oc * oc - kx * kx > 0.f) ? fw : 0.f;
            float2 vv = col[w][kd];
            base[(size_t)kd * N_FC] = make_float2(vv.x * m, vv.y * m);
        }
    }
}

// ---------------- transpose: spec[bc][kd][f] -> spec_t rows [kd][f]{bc0..15, kzr} ----------------
// row stride = 36 floats (32 spec + kzr + 3 pad)
__global__ __launch_bounds__(256) void k_trans(const float2* __restrict__ spec,
                                               float* __restrict__ spec_t){
    int blk = blockIdx.x;           // kd*65 + fb
    int kd = blk / 65, fb = blk - kd * 65;
    __shared__ float2 ld[16][17];
    int tid = threadIdx.x;
    int fi = tid & 15, bc = tid >> 4;
    int f = fb * 16 + fi;
    if (f < N_FC) ld[fi][bc] = spec[((size_t)(bc * 128 + kd)) * N_FC + f];
    __syncthreads();
    int fi2 = tid >> 4, bc2 = tid & 15;
    int f2 = fb * 16 + fi2;
    if (f2 < N_FC){
        float* row = spec_t + (size_t)(kd * N_FC + f2) * 36;
        ((float2*)row)[bc2] = ld[fi2][bc2];
        if (bc2 == 0){
            // kz/(2*pi) in cycles/m: sqrt((f_Hz/c)^2 - (sdx/(N*pitch))^2)
            float fr = (float)f2 * 19531.25f;            // f2 / (2048*2.5e-8) Hz
            float a  = fr * (1.0f / 1540.0f);
            int sdx  = (kd < 64) ? kd : kd - 128;
            float b  = (float)sdx * (1.0f / (128.0f * 3.0e-4f));
            float kq = a * a - b * b;
            row[32] = (kq > 0.f) ? sqrtf(kq) : 0.f;
        }
    }
}

// ---------------- band: lane=y, serial f, 16 bc accumulators, direct sincos phase ----------------
__device__ __forceinline__ void bandstep(const float4* b, float ym,
                                         float* aR, float* aI){
    float kzr = b[8].x;
    float t  = ym * kzr;
    float tf = t - floorf(t);
    float s  = sin_rev(tf);
    float c  = cos_rev(tf);
    #pragma unroll
    for (int j = 0; j < 8; ++j){
        float4 v = b[j];
        aR[2*j]   += v.x * c - v.y * s;
        aI[2*j]   += v.x * s + v.y * c;
        aR[2*j+1] += v.z * c - v.w * s;
        aI[2*j+1] += v.z * s + v.w * c;
    }
}

#define LR(X, r) { _Pragma("unroll") for (int j = 0; j < 9; ++j) X[j] = rp[(size_t)(r) * 9 + j]; }

__global__ __launch_bounds__(64) void k_band(const float* __restrict__ spec_t,
                                             float2* __restrict__ band_p){
    int wid  = blockIdx.x;           // 2048 waves: kd*16 + fc*4 + yc
    int lane = threadIdx.x;
    int yc = wid & 3;
    int fc = (wid >> 2) & 3;
    int kd = wid >> 4;
    int y  = yc * 64 + lane;
    float ym = 1.0e-3f + 1.5e-4f * (float)y;
    int f0 = fc * 256;
    int nf = (fc == 3) ? 257 : 256;
    const float4* rp = (const float4*)spec_t + (size_t)(kd * N_FC + f0) * 9;
    float aR[16], aI[16];
    #pragma unroll
    for (int i = 0; i < 16; ++i){ aR[i] = 0.f; aI[i] = 0.f; }
    float4 A[9], B[9], C[9];
    LR(A, 0); LR(B, 1);
    int it = 0;
    for (; it + 3 <= nf; it += 3){
        LR(C, it + 2); bandstep(A, ym, aR, aI);
        LR(A, it + 3); bandstep(B, ym, aR, aI);
        LR(B, it + 4); bandstep(C, ym, aR, aI);
    }
    if (it < nf){
        bandstep(A, ym, aR, aI); ++it;
        if (it < nf){ bandstep(B, ym, aR, aI); }
    }
    float2* bp = band_p + ((size_t)(fc * 128 + kd) * 16) * 256 + y;
    #pragma unroll
    for (int bc = 0; bc < 16; ++bc)
        bp[(size_t)bc * 256] = make_float2(aR[bc], aI[bc]);
}

// ---------------- final: sum 4 f-partials, 128-pt inverse DFT over kd, magnitude ----------------
__global__ __launch_bounds__(256) void k_final(const float2* __restrict__ band_p,
                                               const float* __restrict__ stat,
                                               float* __restrict__ out){
    int blk = blockIdx.x;            // bc*32 + yt
    int bc = blk >> 5, yt = blk & 31;
    __shared__ float2 ld[128][9];
    int tid = threadIdx.x;
    #pragma unroll
    for (int k2 = 0; k2 < 4; ++k2){
        int idx = tid + k2 * 256;
        int kd = idx >> 3, yi = idx & 7;
        float2 s = make_float2(0.f, 0.f);
        #pragma unroll
        for (int p = 0; p < 4; ++p){
            float2 v = band_p[(((size_t)(p * 128 + kd) * 16) + bc) * 256 + yt * 8 + yi];
            s.x += v.x; s.y += v.y;
        }
        ld[kd][yi] = s;
    }
    __syncthreads();
    int x = tid & 127, h = tid >> 7;
    float ang = (float)(2.0 * M_PI / 128.0) * (float)x;
    float sn, cs; sincosf(ang, &sn, &cs);
    float2 w = make_float2(cs, sn);
    float2 p = make_float2(1.f, 0.f);
    float aR[4] = {0.f,0.f,0.f,0.f}, aI[4] = {0.f,0.f,0.f,0.f};
    for (int kd = 0; kd < 128; ++kd){
        #pragma unroll
        for (int q = 0; q < 4; ++q){
            float2 b = ld[kd][h * 4 + q];
            aR[q] += b.x * p.x - b.y * p.y;
            aI[q] += b.x * p.y + b.y * p.x;
        }
        p = cmulf(p, w);
    }
    float invnorm = 1.f / (fmaxf(stat[32], 1.1920929e-7f) * 2048.f);
    #pragma unroll
    for (int q = 0; q < 4; ++q){
        int y = yt * 8 + h * 4 + q;
        out[((size_t)bc * 256 + y) * 128 + x] = sqrtf(aR[q]*aR[q] + aI[q]*aI[q]) * invnorm;
    }
}

extern "C" void kernel_launch(void* const* d_in, const int* in_sizes, int n_in,
                              void* d_out, int out_size, void* d_ws, size_t ws_size,
                              hipStream_t stream){
    const float* sino = (const float*)d_in[0];
    const float* apod = (const float*)d_in[1];
    float* out = (float*)d_out;
    float* W = (float*)d_ws;
    // workspace layout (floats):
    //   [0..63]        stat (mean[16], invstd[16], apodsum)
    //   [64..1087]     psum
    //   [1088..2111]   psq
    //   [2112..]       spec (16*128*1025 float2 = 4,198,400 floats)  -- later aliased by band_p
    //   then           spec_t ((128*1025+2) rows * 36 floats = 4,723,272 floats)
    float* psum = W + 64;
    float* psq  = W + 1088;
    float2* spec   = (float2*)(W + 2112);
    float*  spec_t = W + 2112 + 4198400;
    float2* band_p = spec;   // alias: spec is dead after k_trans; band_p = 4*128*16*256 float2 fits

    k_stats1<<<NBCC * 64, 256, 0, stream>>>(sino, psum, psq);
    k_stats2<<<NBCC, 64, 0, stream>>>(psum, psq, apod, W);
    k_tfft  <<<NBCC * N_DETC, 256, 0, stream>>>(sino, apod, W, spec);
    k_dfft  <<<NBCC * 257, 256, 0, stream>>>(spec);
    k_trans <<<N_DETC * 65, 256, 0, stream>>>(spec, spec_t);
    k_band  <<<2048, 64, 0, stream>>>(spec_t, band_p);
    k_final <<<NBCC * 32, 256, 0, stream>>>(band_p, W, out);
}

// Round 5
// 202.390 us; speedup vs baseline: 2.6462x; 1.1442x over previous
//
#include <hip/hip_runtime.h>
#include <math.h>

#define N_DETC 128
#define N_TC   2048
#define N_FC   1025
#define NXC    128
#define NYC    256
#define NBCC   16     // B*C = 8*2

__device__ __forceinline__ float2 cmulf(float2 a, float2 b){
    return make_float2(a.x*b.x - a.y*b.y, a.x*b.y + a.y*b.x);
}

#if __has_builtin(__builtin_amdgcn_sinf) && __has_builtin(__builtin_amdgcn_cosf)
__device__ __forceinline__ float sin_rev(float tf){ return __builtin_amdgcn_sinf(tf); }   // sin(2*pi*tf)
__device__ __forceinline__ float cos_rev(float tf){ return __builtin_amdgcn_cosf(tf); }
#else
__device__ __forceinline__ float sin_rev(float tf){ return __sinf(6.28318530718f * tf); }
__device__ __forceinline__ float cos_rev(float tf){ return __cosf(6.28318530718f * tf); }
#endif

// ---------------- stats stage 1: per-(bc,chunk) partial sums, float4 loads ----------------
__global__ __launch_bounds__(256) void k_stats1(const float* __restrict__ sino,
                                                float* __restrict__ psum,
                                                float* __restrict__ psq){
    int bc    = blockIdx.x >> 6;
    int chunk = blockIdx.x & 63;
    const float4* p = (const float4*)(sino + (size_t)bc * (N_DETC * N_TC)) + (size_t)chunk * 1024;
    float s = 0.f, q = 0.f;
    #pragma unroll
    for (int i = 0; i < 4; ++i){
        float4 v = p[threadIdx.x + i * 256];
        s += v.x + v.y + v.z + v.w;
        q += v.x*v.x + v.y*v.y + v.z*v.z + v.w*v.w;
    }
    #pragma unroll
    for (int m = 1; m < 64; m <<= 1){
        s += __shfl_xor(s, m, 64);
        q += __shfl_xor(q, m, 64);
    }
    __shared__ float ls[4], lq[4];
    int w = threadIdx.x >> 6, lane = threadIdx.x & 63;
    if (lane == 0){ ls[w] = s; lq[w] = q; }
    __syncthreads();
    if (threadIdx.x == 0){
        psum[blockIdx.x] = ls[0] + ls[1] + ls[2] + ls[3];
        psq[blockIdx.x]  = lq[0] + lq[1] + lq[2] + lq[3];
    }
}

// ---------------- stats stage 2: finalize mean & inv-std per bc; bc0 also sums apod ----------------
__global__ void k_stats2(const float* __restrict__ psum,
                         const float* __restrict__ psq,
                         const float* __restrict__ apod,
                         float* __restrict__ stat){
    int bc = blockIdx.x, t = threadIdx.x;   // 64 threads
    float s = psum[bc * 64 + t], q = psq[bc * 64 + t];
    float a = (bc == 0) ? (apod[t] + apod[t + 64]) : 0.f;
    #pragma unroll
    for (int m = 1; m < 64; m <<= 1){
        s += __shfl_xor(s, m, 64);
        q += __shfl_xor(q, m, 64);
        a += __shfl_xor(a, m, 64);
    }
    if (t == 0){
        const float inv_n = 1.f / (float)(N_DETC * N_TC);
        float mean = s * inv_n;
        float var  = q * inv_n - mean * mean;
        stat[bc]      = mean;
        stat[16 + bc] = rsqrtf(fmaxf(var, 0.f) + 1.1920929e-7f);
        if (bc == 0) stat[32] = a;
    }
}

// ---------------- temporal FFT: 2048-pt complex FFT (imag=0), keep bins 0..1024 ----------------
__global__ __launch_bounds__(256) void k_tfft(const float* __restrict__ sino,
                                              const float* __restrict__ apod,
                                              const float* __restrict__ stat,
                                              float2* __restrict__ spec){
    int row = blockIdx.x;            // bc*128 + d
    int bc = row >> 7, d = row & 127;
    __shared__ float2 a[N_TC];       // 16 KB
    float mean = stat[bc];
    float scl  = stat[16 + bc] * apod[d];
    const float* p = sino + (size_t)row * N_TC;
    for (int t = threadIdx.x; t < N_TC; t += 256){
        float v = (p[t] - mean) * scl;
        int r = __brev((unsigned)t) >> 21;   // 11-bit reverse
        a[r] = make_float2(v, 0.f);
    }
    __syncthreads();
    for (int s = 1; s <= 11; ++s){
        int half = 1 << (s - 1);
        for (int j = threadIdx.x; j < N_TC / 2; j += 256){
            int g = j >> (s - 1);
            int k = j & (half - 1);
            int i1 = (g << s) + k;
            int i2 = i1 + half;
            float ang = -(float)M_PI * (float)k / (float)half;   // -2*pi*k/m
            float sn, cs; __sincosf(ang, &sn, &cs);
            float2 u = a[i1], v = a[i2];
            float2 t = make_float2(v.x * cs - v.y * sn, v.x * sn + v.y * cs);
            a[i1] = make_float2(u.x + t.x, u.y + t.y);
            a[i2] = make_float2(u.x - t.x, u.y - t.y);
        }
        __syncthreads();
    }
    float2* o = spec + (size_t)row * N_FC;
    for (int f = threadIdx.x; f < N_FC; f += 256) o[f] = a[f];
}

// ---------------- detector FFT (128-pt, in-place over d axis) + mask & freq weight ----------------
__global__ __launch_bounds__(256) void k_dfft(float2* __restrict__ spec){
    int bc = blockIdx.x / 257;
    int fg = blockIdx.x - bc * 257;
    int w    = threadIdx.x >> 6;     // wave id 0..3 -> one f column each
    int lane = threadIdx.x & 63;
    int ftry = fg * 4 + w;
    bool valid = (ftry <= 1024);
    int f = valid ? ftry : 1024;
    __shared__ float2 col[4][128];
    float2* base = spec + (size_t)bc * 128 * N_FC + f;
    col[w][__brev((unsigned)lane) >> 25]        = base[(size_t)lane * N_FC];
    col[w][__brev((unsigned)(lane + 64)) >> 25] = base[(size_t)(lane + 64) * N_FC];
    __syncthreads();
    for (int s = 1; s <= 7; ++s){
        int half = 1 << (s - 1);
        int g = lane >> (s - 1);
        int k = lane & (half - 1);
        int i1 = (g << s) + k;
        int i2 = i1 + half;
        float ang = -(float)M_PI * (float)k / (float)half;
        float sn, cs; __sincosf(ang, &sn, &cs);
        float2 u = col[w][i1], v = col[w][i2];
        float2 t = make_float2(v.x * cs - v.y * sn, v.x * sn + v.y * cs);
        col[w][i1] = make_float2(u.x + t.x, u.y + t.y);
        col[w][i2] = make_float2(u.x - t.x, u.y - t.y);
        __syncthreads();
    }
    if (valid){
        float freqf = (float)((double)f / (2048.0 * 2.5e-8));
        float omega = (float)(2.0 * M_PI) * freqf;
        float oc = omega / 1540.0f;
        float fw = (f == 0 || f == 1024) ? 1.f : 2.f;
        #pragma unroll
        for (int kk = 0; kk < 2; ++kk){
            int kd = lane + kk * 64;
            int sdx = (kd < 64) ? kd : kd - 128;
            float kx = (float)(2.0 * M_PI * ((double)sdx / (128.0 * 3.0e-4)));
            float m = (oc * oc - kx * kx > 0.f) ? fw : 0.f;
            float2 vv = col[w][kd];
            base[(size_t)kd * N_FC] = make_float2(vv.x * m, vv.y * m);
        }
    }
}

// ---------------- transpose: spec[bc][kd][f] -> spec_t rows [kd][f]{bc0..15, kzr} ----------------
// row stride = 36 floats (32 spec + kzr + 3 pad)
__global__ __launch_bounds__(256) void k_trans(const float2* __restrict__ spec,
                                               float* __restrict__ spec_t){
    int blk = blockIdx.x;           // kd*65 + fb
    int kd = blk / 65, fb = blk - kd * 65;
    __shared__ float2 ld[16][17];
    int tid = threadIdx.x;
    int fi = tid & 15, bc = tid >> 4;
    int f = fb * 16 + fi;
    if (f < N_FC) ld[fi][bc] = spec[((size_t)(bc * 128 + kd)) * N_FC + f];
    __syncthreads();
    int fi2 = tid >> 4, bc2 = tid & 15;
    int f2 = fb * 16 + fi2;
    if (f2 < N_FC){
        float* row = spec_t + (size_t)(kd * N_FC + f2) * 36;
        ((float2*)row)[bc2] = ld[fi2][bc2];
        if (bc2 == 0){
            // kz/(2*pi) in cycles/m
            float fr = (float)f2 * 19531.25f;            // Hz
            float a  = fr * (1.0f / 1540.0f);
            int sdx  = (kd < 64) ? kd : kd - 128;
            float b  = (float)sdx * (1.0f / (128.0f * 3.0e-4f));
            float kq = a * a - b * b;
            row[32] = (kq > 0.f) ? sqrtf(kq) : 0.f;
        }
    }
}

// ---------------- band: wave=(kd,bch,fc); lane holds 4 y (y=lane+64*qy), 8 bc accumulators ----------------
__global__ __launch_bounds__(256, 4) void k_band(const float* __restrict__ spec_t,
                                                 float2* __restrict__ band_p){
    int blk = blockIdx.x;               // kd*8 + bch*4 + q
    int q   = blk & 3;
    int bch = (blk >> 2) & 1;
    int kd  = blk >> 3;
    int w    = __builtin_amdgcn_readfirstlane(threadIdx.x >> 6);
    int lane = threadIdx.x & 63;
    int fc  = q * 4 + w;                // 0..15
    int f0  = fc * 64;
    int nf  = (fc == 15) ? 65 : 64;
    const float* rp = spec_t + ((size_t)kd * N_FC + f0) * 36 + bch * 16;

    float ym[4];
    #pragma unroll
    for (int qy = 0; qy < 4; ++qy) ym[qy] = 1.0e-3f + 1.5e-4f * (float)(lane + 64 * qy);

    float aR[32], aI[32];
    #pragma unroll
    for (int i = 0; i < 32; ++i){ aR[i] = 0.f; aI[i] = 0.f; }

    // 2-deep register pipeline: cur / nxt (5 loads per row: 4x float4 + kzr)
    float4 c0 = ((const float4*)rp)[0], c1 = ((const float4*)rp)[1];
    float4 c2 = ((const float4*)rp)[2], c3 = ((const float4*)rp)[3];
    float ckz = rp[16 + (16 - bch * 16)];   // kzr at row offset 32 = bch*16 + (32 - bch*16)
    // simpler: kzr is at (rp - bch*16)[32]
    ckz = (rp - bch * 16)[32];

    for (int it = 0; it < nf; ++it){
        const float* np = rp + 36;
        float4 n0 = ((const float4*)np)[0], n1 = ((const float4*)np)[1];
        float4 n2 = ((const float4*)np)[2], n3 = ((const float4*)np)[3];
        float nkz = (np - bch * 16)[32];

        #pragma unroll
        for (int qy = 0; qy < 4; ++qy){
            float t  = ym[qy] * ckz;
            float tf = t - floorf(t);
            float s  = sin_rev(tf);
            float c  = cos_rev(tf);
            aR[0*4+qy] += c0.x * c - c0.y * s;  aI[0*4+qy] += c0.x * s + c0.y * c;
            aR[1*4+qy] += c0.z * c - c0.w * s;  aI[1*4+qy] += c0.z * s + c0.w * c;
            aR[2*4+qy] += c1.x * c - c1.y * s;  aI[2*4+qy] += c1.x * s + c1.y * c;
            aR[3*4+qy] += c1.z * c - c1.w * s;  aI[3*4+qy] += c1.z * s + c1.w * c;
            aR[4*4+qy] += c2.x * c - c2.y * s;  aI[4*4+qy] += c2.x * s + c2.y * c;
            aR[5*4+qy] += c2.z * c - c2.w * s;  aI[5*4+qy] += c2.z * s + c2.w * c;
            aR[6*4+qy] += c3.x * c - c3.y * s;  aI[6*4+qy] += c3.x * s + c3.y * c;
            aR[7*4+qy] += c3.z * c - c3.w * s;  aI[7*4+qy] += c3.z * s + c3.w * c;
        }
        c0 = n0; c1 = n1; c2 = n2; c3 = n3; ckz = nkz;
        rp = np;
    }

    // block reduction across 4 waves (w = fc sub-chunks) in LDS
    __shared__ float2 red[2][2048];     // [slot][bc'*256 + y] , 32 KB
    float2* slot = red[w & 1];
    if (w < 2){
        #pragma unroll
        for (int b = 0; b < 8; ++b)
            #pragma unroll
            for (int qy = 0; qy < 4; ++qy)
                slot[b * 256 + qy * 64 + lane] = make_float2(aR[b*4+qy], aI[b*4+qy]);
    }
    __syncthreads();
    if (w >= 2){
        #pragma unroll
        for (int b = 0; b < 8; ++b)
            #pragma unroll
            for (int qy = 0; qy < 4; ++qy){
                float2 v = slot[b * 256 + qy * 64 + lane];
                v.x += aR[b*4+qy]; v.y += aI[b*4+qy];
                slot[b * 256 + qy * 64 + lane] = v;
            }
    }
    __syncthreads();
    int t = threadIdx.x;
    float2* ob = band_p + ((size_t)(q * 128 + kd) * 16 + bch * 8) * 256;
    #pragma unroll
    for (int i = 0; i < 8; ++i){
        int idx = i * 256 + t;
        float2 v0 = red[0][idx], v1 = red[1][idx];
        ob[idx] = make_float2(v0.x + v1.x, v0.y + v1.y);
    }
}

// ---------------- final: sum 4 f-partials, 128-pt inverse DFT over kd, magnitude ----------------
__global__ __launch_bounds__(256) void k_final(const float2* __restrict__ band_p,
                                               const float* __restrict__ stat,
                                               float* __restrict__ out){
    int blk = blockIdx.x;            // bc*32 + yt
    int bc = blk >> 5, yt = blk & 31;
    __shared__ float2 ld[128][9];
    int tid = threadIdx.x;
    #pragma unroll
    for (int k2 = 0; k2 < 4; ++k2){
        int idx = tid + k2 * 256;
        int kd = idx >> 3, yi = idx & 7;
        float2 s = make_float2(0.f, 0.f);
        #pragma unroll
        for (int p = 0; p < 4; ++p){
            float2 v = band_p[(((size_t)(p * 128 + kd) * 16) + bc) * 256 + yt * 8 + yi];
            s.x += v.x; s.y += v.y;
        }
        ld[kd][yi] = s;
    }
    __syncthreads();
    int x = tid & 127, h = tid >> 7;
    float ang = (float)(2.0 * M_PI / 128.0) * (float)x;
    float sn, cs; sincosf(ang, &sn, &cs);
    float2 w = make_float2(cs, sn);
    float2 p = make_float2(1.f, 0.f);
    float aR[4] = {0.f,0.f,0.f,0.f}, aI[4] = {0.f,0.f,0.f,0.f};
    for (int kd = 0; kd < 128; ++kd){
        #pragma unroll
        for (int qq = 0; qq < 4; ++qq){
            float2 b = ld[kd][h * 4 + qq];
            aR[qq] += b.x * p.x - b.y * p.y;
            aI[qq] += b.x * p.y + b.y * p.x;
        }
        p = cmulf(p, w);
    }
    float invnorm = 1.f / (fmaxf(stat[32], 1.1920929e-7f) * 2048.f);
    #pragma unroll
    for (int qq = 0; qq < 4; ++qq){
        int y = yt * 8 + h * 4 + qq;
        out[((size_t)bc * 256 + y) * 128 + x] = sqrtf(aR[qq]*aR[qq] + aI[qq]*aI[qq]) * invnorm;
    }
}

extern "C" void kernel_launch(void* const* d_in, const int* in_sizes, int n_in,
                              void* d_out, int out_size, void* d_ws, size_t ws_size,
                              hipStream_t stream){
    const float* sino = (const float*)d_in[0];
    const float* apod = (const float*)d_in[1];
    float* out = (float*)d_out;
    float* W = (float*)d_ws;
    // workspace layout (floats):
    //   [0..63]        stat (mean[16], invstd[16], apodsum)
    //   [64..1087]     psum
    //   [1088..2111]   psq
    //   [2112..]       spec (16*128*1025 float2 = 4,198,400 floats)  -- later aliased by band_p
    //   then           spec_t ((128*1025+2) rows * 36 floats)
    float* psum = W + 64;
    float* psq  = W + 1088;
    float2* spec   = (float2*)(W + 2112);
    float*  spec_t = W + 2112 + 4198400;
    float2* band_p = spec;   // alias: spec dead after k_trans; band_p = 4*128*16*256 float2 fits

    k_stats1<<<NBCC * 64, 256, 0, stream>>>(sino, psum, psq);
    k_stats2<<<NBCC, 64, 0, stream>>>(psum, psq, apod, W);
    k_tfft  <<<NBCC * N_DETC, 256, 0, stream>>>(sino, apod, W, spec);
    k_dfft  <<<NBCC * 257, 256, 0, stream>>>(spec);
    k_trans <<<N_DETC * 65, 256, 0, stream>>>(spec, spec_t);
    k_band  <<<1024, 256, 0, stream>>>(spec_t, band_p);
    k_final <<<NBCC * 32, 256, 0, stream>>>(band_p, W, out);
}

// Round 6
// 134.211 us; speedup vs baseline: 3.9905x; 1.5080x over previous
//
#include <hip/hip_runtime.h>
#include <math.h>

#define N_DETC 128
#define N_TC   2048
#define N_FC   1025
#define NXC    128
#define NYC    256
#define NBCC   16     // B*C = 8*2

__device__ __forceinline__ float2 cmulf(float2 a, float2 b){
    return make_float2(a.x*b.x - a.y*b.y, a.x*b.y + a.y*b.x);
}

#if __has_builtin(__builtin_amdgcn_sinf) && __has_builtin(__builtin_amdgcn_cosf)
__device__ __forceinline__ float sin_rev(float tf){ return __builtin_amdgcn_sinf(tf); }   // sin(2*pi*tf)
__device__ __forceinline__ float cos_rev(float tf){ return __builtin_amdgcn_cosf(tf); }
#else
__device__ __forceinline__ float sin_rev(float tf){ return __sinf(6.28318530718f * tf); }
__device__ __forceinline__ float cos_rev(float tf){ return __cosf(6.28318530718f * tf); }
#endif

// ---------------- stats stage 1 ----------------
__global__ __launch_bounds__(256) void k_stats1(const float* __restrict__ sino,
                                                float* __restrict__ psum,
                                                float* __restrict__ psq){
    int bc    = blockIdx.x >> 6;
    int chunk = blockIdx.x & 63;
    const float4* p = (const float4*)(sino + (size_t)bc * (N_DETC * N_TC)) + (size_t)chunk * 1024;
    float s = 0.f, q = 0.f;
    #pragma unroll
    for (int i = 0; i < 4; ++i){
        float4 v = p[threadIdx.x + i * 256];
        s += v.x + v.y + v.z + v.w;
        q += v.x*v.x + v.y*v.y + v.z*v.z + v.w*v.w;
    }
    #pragma unroll
    for (int m = 1; m < 64; m <<= 1){
        s += __shfl_xor(s, m, 64);
        q += __shfl_xor(q, m, 64);
    }
    __shared__ float ls[4], lq[4];
    int w = threadIdx.x >> 6, lane = threadIdx.x & 63;
    if (lane == 0){ ls[w] = s; lq[w] = q; }
    __syncthreads();
    if (threadIdx.x == 0){
        psum[blockIdx.x] = ls[0] + ls[1] + ls[2] + ls[3];
        psq[blockIdx.x]  = lq[0] + lq[1] + lq[2] + lq[3];
    }
}

// ---------------- stats stage 2 ----------------
__global__ void k_stats2(const float* __restrict__ psum,
                         const float* __restrict__ psq,
                         const float* __restrict__ apod,
                         float* __restrict__ stat){
    int bc = blockIdx.x, t = threadIdx.x;   // 64 threads
    float s = psum[bc * 64 + t], q = psq[bc * 64 + t];
    float a = (bc == 0) ? (apod[t] + apod[t + 64]) : 0.f;
    #pragma unroll
    for (int m = 1; m < 64; m <<= 1){
        s += __shfl_xor(s, m, 64);
        q += __shfl_xor(q, m, 64);
        a += __shfl_xor(a, m, 64);
    }
    if (t == 0){
        const float inv_n = 1.f / (float)(N_DETC * N_TC);
        float mean = s * inv_n;
        float var  = q * inv_n - mean * mean;
        stat[bc]      = mean;
        stat[16 + bc] = rsqrtf(fmaxf(var, 0.f) + 1.1920929e-7f);
        if (bc == 0) stat[32] = a;
    }
}

// ---------------- temporal FFT ----------------
__global__ __launch_bounds__(256) void k_tfft(const float* __restrict__ sino,
                                              const float* __restrict__ apod,
                                              const float* __restrict__ stat,
                                              float2* __restrict__ spec){
    int row = blockIdx.x;            // bc*128 + d
    int bc = row >> 7, d = row & 127;
    __shared__ float2 a[N_TC];       // 16 KB
    float mean = stat[bc];
    float scl  = stat[16 + bc] * apod[d];
    const float* p = sino + (size_t)row * N_TC;
    for (int t = threadIdx.x; t < N_TC; t += 256){
        float v = (p[t] - mean) * scl;
        int r = __brev((unsigned)t) >> 21;   // 11-bit reverse
        a[r] = make_float2(v, 0.f);
    }
    __syncthreads();
    for (int s = 1; s <= 11; ++s){
        int half = 1 << (s - 1);
        for (int j = threadIdx.x; j < N_TC / 2; j += 256){
            int g = j >> (s - 1);
            int k = j & (half - 1);
            int i1 = (g << s) + k;
            int i2 = i1 + half;
            float ang = -(float)M_PI * (float)k / (float)half;
            float sn, cs; __sincosf(ang, &sn, &cs);
            float2 u = a[i1], v = a[i2];
            float2 t = make_float2(v.x * cs - v.y * sn, v.x * sn + v.y * cs);
            a[i1] = make_float2(u.x + t.x, u.y + t.y);
            a[i2] = make_float2(u.x - t.x, u.y - t.y);
        }
        __syncthreads();
    }
    float2* o = spec + (size_t)row * N_FC;
    for (int f = threadIdx.x; f < N_FC; f += 256) o[f] = a[f];
}

// ---------------- fused detector FFT + mask/weight + transpose + kzJ table ----------------
// block = one f; LDS holds all 16 bc x 128 kd; writes spec_th rows [h][kd][f]{8bc float2}
// and kzJ[kd][f] = (kz_rev, Jr, Ji, 0) with J = exp(i*2pi*64*DY*kz_rev)
__global__ __launch_bounds__(256) void k_dft(const float2* __restrict__ spec,
                                             float* __restrict__ spec_th,
                                             float4* __restrict__ kzJ){
    int bid = blockIdx.x;
    int f = (bid < 1024) ? ((bid & 7) * 128 + (bid >> 3)) : 1024;  // XCD-contiguous f ranges
    __shared__ float2 col[16][128];   // 16 KB
    int tid = threadIdx.x;
    #pragma unroll
    for (int k2 = 0; k2 < 8; ++k2){
        int idx = tid + (k2 << 8);            // 0..2047
        int bc = idx >> 7, kd = idx & 127;
        col[bc][__brev((unsigned)kd) >> 25] = spec[((size_t)(bc * 128 + kd)) * N_FC + f];
    }
    float fr = (float)f * 19531.25f;          // Hz
    float oc = fr * (1.0f / 1540.0f);         // cycles/m
    if (tid < 128){
        int kd = tid;
        int sdx = (kd < 64) ? kd : kd - 128;
        float b = (float)sdx * 26.0416666f;   // 1/(128*3e-4) cycles/m
        float kq = oc * oc - b * b;
        float kzr = (kq > 0.f) ? sqrtf(kq) : 0.f;
        float tj = 9.6e-3f * kzr;             // 64*DY*kz in revolutions
        tj -= floorf(tj);
        kzJ[(size_t)kd * N_FC + f] = make_float4(kzr, cos_rev(tj), sin_rev(tj), 0.f);
    }
    __syncthreads();
    for (int s = 1; s <= 7; ++s){
        int half = 1 << (s - 1);
        #pragma unroll
        for (int k2 = 0; k2 < 4; ++k2){
            int j = tid + (k2 << 8);          // 0..1023 : bc*64 + butterfly
            int bc = j >> 6, jj = j & 63;
            int g = jj >> (s - 1);
            int k = jj & (half - 1);
            int i1 = (g << s) + k;
            int i2 = i1 + half;
            float ang = -(float)M_PI * (float)k / (float)half;
            float sn, cs; __sincosf(ang, &sn, &cs);
            float2 u = col[bc][i1], v = col[bc][i2];
            float2 t = make_float2(v.x * cs - v.y * sn, v.x * sn + v.y * cs);
            col[bc][i1] = make_float2(u.x + t.x, u.y + t.y);
            col[bc][i2] = make_float2(u.x - t.x, u.y - t.y);
        }
        __syncthreads();
    }
    float fw = (f == 0 || f == 1024) ? 1.f : 2.f;
    #pragma unroll
    for (int k2 = 0; k2 < 8; ++k2){
        int idx = tid + (k2 << 8);            // 0..2047
        int bc = idx & 15, kd = idx >> 4;
        int sdx = (kd < 64) ? kd : kd - 128;
        float b = (float)sdx * 26.0416666f;
        float m = (oc * oc - b * b > 0.f) ? fw : 0.f;
        float2 v = col[bc][kd];
        int h = bc >> 3;
        float* dst = spec_th + ((size_t)h * (128 * N_FC) + (size_t)kd * N_FC + f) * 16 + ((bc & 7) << 1);
        *(float2*)dst = make_float2(v.x * m, v.y * m);
    }
}

// ---------------- band: wave=(kd,bch,fc); lane=y base, J-chain over 4 y-quads ----------------
__global__ __launch_bounds__(256, 4) void k_band(const float* __restrict__ spec_th,
                                                 const float4* __restrict__ kzJ,
                                                 float2* __restrict__ band_p){
    int blk = blockIdx.x;               // kd*8 + bch*4 + q
    int q   = blk & 3;
    int bch = (blk >> 2) & 1;
    int kd  = blk >> 3;
    int w    = __builtin_amdgcn_readfirstlane(threadIdx.x >> 6);
    int lane = threadIdx.x & 63;
    int fc  = q * 4 + w;                // 0..15
    int f0  = fc * 64;
    int nf  = (fc == 15) ? 65 : 64;
    const float4* sp = (const float4*)(spec_th + ((size_t)bch * 128 * N_FC + (size_t)kd * N_FC + f0) * 16);
    const float4* kj = kzJ + (size_t)kd * N_FC + f0;

    float ym0 = 1.0e-3f + 1.5e-4f * (float)lane;

    float aR[8][4], aI[8][4];
    #pragma unroll
    for (int b = 0; b < 8; ++b)
        #pragma unroll
        for (int qy = 0; qy < 4; ++qy){ aR[b][qy] = 0.f; aI[b][qy] = 0.f; }

    float4 ca = sp[0], cb = sp[1], cc = sp[2], cd = sp[3];
    float4 ck = kj[0];

    for (int it = 0; it < nf; ++it){
        const float4* spn = sp + 4;
        float4 na = spn[0], nb = spn[1], nc = spn[2], nd = spn[3];
        float4 nk = kj[it + 1];

        float t  = ym0 * ck.x;
        float tf = t - floorf(t);
        float ps = sin_rev(tf);
        float pc = cos_rev(tf);
        float Jr = ck.y, Ji = ck.z;
        float cre[8] = {ca.x, ca.z, cb.x, cb.z, cc.x, cc.z, cd.x, cd.z};
        float cim[8] = {ca.y, ca.w, cb.y, cb.w, cc.y, cc.w, cd.y, cd.w};

        #pragma unroll
        for (int qy = 0; qy < 4; ++qy){
            #pragma unroll
            for (int b = 0; b < 8; ++b){
                aR[b][qy] = fmaf(cre[b], pc, aR[b][qy]);
                aR[b][qy] = fmaf(-cim[b], ps, aR[b][qy]);
                aI[b][qy] = fmaf(cre[b], ps, aI[b][qy]);
                aI[b][qy] = fmaf(cim[b], pc, aI[b][qy]);
            }
            if (qy < 3){
                float t1 = pc * Jr;
                float npc = fmaf(-ps, Ji, t1);
                float t2 = pc * Ji;
                float nps = fmaf(ps, Jr, t2);
                pc = npc; ps = nps;
            }
        }
        ca = na; cb = nb; cc = nc; cd = nd; ck = nk;
        sp = spn;
    }

    // block reduction across 4 waves (fc sub-chunks)
    __shared__ float2 red[2][2048];     // 32 KB
    float2* slot = red[w & 1];
    if (w < 2){
        #pragma unroll
        for (int b = 0; b < 8; ++b)
            #pragma unroll
            for (int qy = 0; qy < 4; ++qy)
                slot[b * 256 + qy * 64 + lane] = make_float2(aR[b][qy], aI[b][qy]);
    }
    __syncthreads();
    if (w >= 2){
        #pragma unroll
        for (int b = 0; b < 8; ++b)
            #pragma unroll
            for (int qy = 0; qy < 4; ++qy){
                float2 v = slot[b * 256 + qy * 64 + lane];
                v.x += aR[b][qy]; v.y += aI[b][qy];
                slot[b * 256 + qy * 64 + lane] = v;
            }
    }
    __syncthreads();
    int t = threadIdx.x;
    float2* ob = band_p + ((size_t)(q * 128 + kd) * 16 + bch * 8) * 256;
    #pragma unroll
    for (int i = 0; i < 8; ++i){
        int idx = i * 256 + t;
        float2 v0 = red[0][idx], v1 = red[1][idx];
        ob[idx] = make_float2(v0.x + v1.x, v0.y + v1.y);
    }
}

// ---------------- final: sum 4 f-partials, 128-pt inverse DFT over kd, magnitude ----------------
__global__ __launch_bounds__(256) void k_final(const float2* __restrict__ band_p,
                                               const float* __restrict__ stat,
                                               float* __restrict__ out){
    int blk = blockIdx.x;            // bc*32 + yt
    int bc = blk >> 5, yt = blk & 31;
    __shared__ float2 ld[128][9];
    int tid = threadIdx.x;
    #pragma unroll
    for (int k2 = 0; k2 < 4; ++k2){
        int idx = tid + k2 * 256;
        int kd = idx >> 3, yi = idx & 7;
        float2 s = make_float2(0.f, 0.f);
        #pragma unroll
        for (int p = 0; p < 4; ++p){
            float2 v = band_p[(((size_t)(p * 128 + kd) * 16) + bc) * 256 + yt * 8 + yi];
            s.x += v.x; s.y += v.y;
        }
        ld[kd][yi] = s;
    }
    __syncthreads();
    int x = tid & 127, h = tid >> 7;
    float ang = (float)(2.0 * M_PI / 128.0) * (float)x;
    float sn, cs; sincosf(ang, &sn, &cs);
    float2 w = make_float2(cs, sn);
    float2 p = make_float2(1.f, 0.f);
    float aR[4] = {0.f,0.f,0.f,0.f}, aI[4] = {0.f,0.f,0.f,0.f};
    for (int kd = 0; kd < 128; ++kd){
        #pragma unroll
        for (int qq = 0; qq < 4; ++qq){
            float2 b = ld[kd][h * 4 + qq];
            aR[qq] += b.x * p.x - b.y * p.y;
            aI[qq] += b.x * p.y + b.y * p.x;
        }
        p = cmulf(p, w);
    }
    float invnorm = 1.f / (fmaxf(stat[32], 1.1920929e-7f) * 2048.f);
    #pragma unroll
    for (int qq = 0; qq < 4; ++qq){
        int y = yt * 8 + h * 4 + qq;
        out[((size_t)bc * 256 + y) * 128 + x] = sqrtf(aR[qq]*aR[qq] + aI[qq]*aI[qq]) * invnorm;
    }
}

extern "C" void kernel_launch(void* const* d_in, const int* in_sizes, int n_in,
                              void* d_out, int out_size, void* d_ws, size_t ws_size,
                              hipStream_t stream){
    const float* sino = (const float*)d_in[0];
    const float* apod = (const float*)d_in[1];
    float* out = (float*)d_out;
    float* W = (float*)d_ws;
    // workspace layout (floats):
    //   [0..63]        stat
    //   [64..1087]     psum
    //   [1088..2111]   psq
    //   spec    : 16*128*1025*2    = 4,198,400   (dead after k_dft; aliased by band_p)
    //   spec_th : 2*128*1025*16    = 4,198,400
    //   kzJ     : 128*1025*4 + 16  =   524,816
    float* psum = W + 64;
    float* psq  = W + 1088;
    float2* spec    = (float2*)(W + 2112);
    float*  spec_th = W + 2112 + 4198400;
    float4* kzJ     = (float4*)(W + 2112 + 4198400 + 4198400);
    float2* band_p  = spec;   // 4*128*16*256 float2 = 4,194,304 floats <= spec size

    k_stats1<<<NBCC * 64, 256, 0, stream>>>(sino, psum, psq);
    k_stats2<<<NBCC, 64, 0, stream>>>(psum, psq, apod, W);
    k_tfft  <<<NBCC * N_DETC, 256, 0, stream>>>(sino, apod, W, spec);
    k_dft   <<<N_FC, 256, 0, stream>>>(spec, spec_th, kzJ);
    k_band  <<<1024, 256, 0, stream>>>(spec_th, kzJ, band_p);
    k_final <<<NBCC * 32, 256, 0, stream>>>(band_p, W, out);
}